// Round 1
// baseline (11477.790 us; speedup 1.0000x reference)
//
#include <hip/hip_runtime.h>
#include <hip/hip_bf16.h>
#include <stdint.h>

// LSTM: B=64, T=2048, I=256, H=512, O=10 (fp32 in/out)
// Strategy: single persistent cooperative kernel.
//  - 128 WGs x 512 threads. 4 groups x 32 WGs; group g owns batches [16g,16g+16).
//  - WG w in group owns h-cols [16w,16w+16) => gate rows {q*512 + 16w + c}.
//  - Wave wv (8/WG) owns K-slice [64wv,64wv+64) of H and I-slice [32wv,+32) of I.
//  - W_hh held in REGISTERS as bf16 hi/lo split MFMA A-fragments (fp32-accurate
//    3-term product); W_ih in registers as single bf16.
//  - Per step: gates = W_ih@x_t (prefetched) + W_hh@h_t (h broadcast via L3 with
//    agent-scope relaxed atomics + monotonic per-WG flags; ping-pong buffers).
//  - 8-way K-split partials reduced through LDS; 256 threads do activations,
//    keep c-state in registers, write packed (bf16hi|bf16lo) h to global.

#define T_SEQ 2048
#define NB    64
#define IDIM  256
#define HDIM  512
#define NGRP  4
#define BG    16
#define WPG   32
#define NWG   128
#define NTHR  512
#define ODIM  10

typedef float  f32x4  __attribute__((ext_vector_type(4)));
typedef short  short8 __attribute__((ext_vector_type(8)));
typedef float  fl4    __attribute__((ext_vector_type(4)));

union Frag { uint32_t u[4]; short8 v; };

__device__ inline unsigned short f2bf(float f) {
  unsigned int u = __float_as_uint(f);
  u += 0x7FFFu + ((u >> 16) & 1u);          // RNE
  return (unsigned short)(u >> 16);
}
__device__ inline float bf2f(unsigned short s) {
  return __uint_as_float(((unsigned int)s) << 16);
}
__device__ inline float sigm(float x)  { return 1.0f / (1.0f + __expf(-x)); }
__device__ inline float tanh_(float x) { float e = __expf(2.0f * x); return 1.0f - 2.0f / (e + 1.0f); }

__global__ __launch_bounds__(NTHR, 2)
void lstm_persist(const float* __restrict__ x,
                  const float* __restrict__ W_ih,
                  const float* __restrict__ W_hh,
                  const float* __restrict__ b_ih,
                  const float* __restrict__ b_hh,
                  uint32_t* __restrict__ h_pk,     // [grp][par][16b][512] packed hi|lo
                  int*      __restrict__ flags,    // [grp][32w] padded to 16 ints
                  float*    __restrict__ h_lastT)  // [512][64] fp32
{
  __shared__ float ldsC[8][4][16][20];  // [wave][gate q][batch][c(16)+pad4]

  const int bid = blockIdx.x;
  const int g   = bid & 3;           // group
  const int w   = bid >> 2;          // 0..31 within group
  const int tid = threadIdx.x;
  const int wv  = tid >> 6;          // wave 0..7
  const int l   = tid & 63;
  const int l16 = l & 15;
  const int lk  = l >> 4;            // 0..3

  // ---- one-time: W_hh fragments (bf16 hi/lo split) + W_ih fragments ----
  Frag whi[4][2], wlo[4][2], wih[4];
  #pragma unroll
  for (int q = 0; q < 4; ++q) {
    const int row = q * HDIM + w * 16 + l16;            // gate row in [0,2048)
    #pragma unroll
    for (int kt = 0; kt < 2; ++kt) {
      const float* p = W_hh + (size_t)row * HDIM + wv * 64 + kt * 32 + lk * 8;
      #pragma unroll
      for (int pj = 0; pj < 4; ++pj) {
        float a = p[2 * pj], b2 = p[2 * pj + 1];
        unsigned short ha = f2bf(a), hb = f2bf(b2);
        unsigned short la = f2bf(a - bf2f(ha)), lb = f2bf(b2 - bf2f(hb));
        whi[q][kt].u[pj] = (uint32_t)ha | ((uint32_t)hb << 16);
        wlo[q][kt].u[pj] = (uint32_t)la | ((uint32_t)lb << 16);
      }
    }
    const float* pi = W_ih + (size_t)row * IDIM + wv * 32 + lk * 8;
    #pragma unroll
    for (int pj = 0; pj < 4; ++pj)
      wih[q].u[pj] = (uint32_t)f2bf(pi[2 * pj]) | ((uint32_t)f2bf(pi[2 * pj + 1]) << 16);
  }

  // ---- update-role (tid<256): one (c,b) cell each; c-state in a register ----
  const int ub = tid & 15;           // batch within group
  const int uc = tid >> 4;           // col-local 0..15 (valid for tid<256)
  float bias[4];
  float cstate = 0.0f;
  if (tid < 256) {
    #pragma unroll
    for (int q = 0; q < 4; ++q) {
      int row = q * HDIM + w * 16 + uc;
      bias[q] = b_ih[row] + b_hh[row];
    }
  }

  const size_t xbase = ((size_t)(g * BG + l16) * T_SEQ) * IDIM + wv * 32 + lk * 8;
  uint32_t* hpk0 = h_pk + ((size_t)(g * 2 + 0) * BG) * HDIM;
  uint32_t* hpk1 = h_pk + ((size_t)(g * 2 + 1) * BG) * HDIM;
  int* myflag   = flags + (g * WPG + w) * 16;
  int* pollflag = flags + (g * WPG + wv * 4 + (l & 3)) * 16;
  const bool poller = (l < 4);

  for (int t = 0; t < T_SEQ; ++t) {
    // issue x fragment loads early (plain cached loads; x is read-only)
    const float* xp = x + xbase + (size_t)t * IDIM;
    fl4 xa = *(const fl4*)(xp);
    fl4 xb = *(const fl4*)(xp + 4);

    // wait for this wave's K-slice producers (h_t ready)
    if (t > 0) {
      while (true) {
        int fv = t;
        if (poller) fv = __hip_atomic_load(pollflag, __ATOMIC_RELAXED, __HIP_MEMORY_SCOPE_AGENT);
        if (__all(fv >= t)) break;
        __builtin_amdgcn_s_sleep(1);
      }
      asm volatile("" ::: "memory");
    }

    // issue h loads (L2-bypassing agent-scope loads -> L3)
    uint32_t hbuf[16];
    if (t > 0) {
      const uint32_t* hp = ((t & 1) ? hpk1 : hpk0) + (size_t)l16 * HDIM + wv * 64 + lk * 8;
      #pragma unroll
      for (int kt = 0; kt < 2; ++kt)
        #pragma unroll
        for (int j = 0; j < 8; ++j)
          hbuf[kt * 8 + j] =
            __hip_atomic_load(hp + kt * 32 + j, __ATOMIC_RELAXED, __HIP_MEMORY_SCOPE_AGENT);
    }

    // ih term (hides h-load latency)
    float xs[8];
    #pragma unroll
    for (int j = 0; j < 4; ++j) { xs[j] = xa[j]; xs[4 + j] = xb[j]; }
    Frag xf;
    #pragma unroll
    for (int pj = 0; pj < 4; ++pj)
      xf.u[pj] = (uint32_t)f2bf(xs[2 * pj]) | ((uint32_t)f2bf(xs[2 * pj + 1]) << 16);

    f32x4 acc[4];
    #pragma unroll
    for (int q = 0; q < 4; ++q) {
      f32x4 z = {0.f, 0.f, 0.f, 0.f};
      acc[q] = __builtin_amdgcn_mfma_f32_16x16x32_bf16(wih[q].v, xf.v, z, 0, 0, 0);
    }

    // hh term: 3-term split product, accumulate fp32
    if (t > 0) {
      #pragma unroll
      for (int kt = 0; kt < 2; ++kt) {
        Frag hh, hl;
        #pragma unroll
        for (int pj = 0; pj < 4; ++pj) {
          uint32_t e0 = hbuf[kt * 8 + 2 * pj], e1 = hbuf[kt * 8 + 2 * pj + 1];
          hh.u[pj] = __builtin_amdgcn_perm(e1, e0, 0x07060302u);  // hi halves
          hl.u[pj] = __builtin_amdgcn_perm(e1, e0, 0x05040100u);  // lo halves
        }
        #pragma unroll
        for (int q = 0; q < 4; ++q) {
          acc[q] = __builtin_amdgcn_mfma_f32_16x16x32_bf16(whi[q][kt].v, hh.v, acc[q], 0, 0, 0);
          acc[q] = __builtin_amdgcn_mfma_f32_16x16x32_bf16(whi[q][kt].v, hl.v, acc[q], 0, 0, 0);
          acc[q] = __builtin_amdgcn_mfma_f32_16x16x32_bf16(wlo[q][kt].v, hh.v, acc[q], 0, 0, 0);
        }
      }
    }

    // write K-partials: D frag = {col=l16 -> batch, row=lk*4+r -> c}
    #pragma unroll
    for (int q = 0; q < 4; ++q)
      *(f32x4*)&ldsC[wv][q][l16][lk * 4] = acc[q];
    __syncthreads();

    if (tid < 256) {
      float s0 = 0.f, s1 = 0.f, s2 = 0.f, s3 = 0.f;
      #pragma unroll
      for (int v = 0; v < 8; ++v) {
        s0 += ldsC[v][0][ub][uc];
        s1 += ldsC[v][1][ub][uc];
        s2 += ldsC[v][2][ub][uc];
        s3 += ldsC[v][3][ub][uc];
      }
      float ig = sigm(s0 + bias[0]);
      float fg = sigm(s1 + bias[1]);
      float gg = tanh_(s2 + bias[2]);
      float og = sigm(s3 + bias[3]);
      cstate = fg * cstate + ig * gg;
      float hval = og * tanh_(cstate);

      unsigned short hh16 = f2bf(hval);
      unsigned short hl16 = f2bf(hval - bf2f(hh16));
      uint32_t pk = ((uint32_t)hh16 << 16) | (uint32_t)hl16;
      uint32_t* dst = (((t + 1) & 1) ? hpk1 : hpk0) + (size_t)ub * HDIM + w * 16 + uc;
      __hip_atomic_store(dst, pk, __ATOMIC_RELAXED, __HIP_MEMORY_SCOPE_AGENT);
      if (t == T_SEQ - 1)
        h_lastT[(size_t)(w * 16 + uc) * NB + (g * BG + ub)] = hval;
    }
    // __syncthreads drains vmcnt(0) per wave before s_barrier => stores at L3
    __syncthreads();
    if (tid == 0)
      __hip_atomic_store(myflag, t + 1, __ATOMIC_RELAXED, __HIP_MEMORY_SCOPE_AGENT);
  }
}

__global__ void head_fc(const float* __restrict__ h_lastT,
                        const float* __restrict__ W_fc,
                        const float* __restrict__ b_fc,
                        float* __restrict__ out)
{
  const int tid = threadIdx.x;     // 640 threads: 10 waves, wave = one output o
  const int b = tid & 63;
  const int o = __builtin_amdgcn_readfirstlane(tid >> 6);
  float acc = 0.f;
  #pragma unroll 8
  for (int j = 0; j < HDIM; ++j)
    acc += h_lastT[(size_t)j * NB + b] * W_fc[(size_t)o * HDIM + j];
  out[b * ODIM + o] = acc + b_fc[o];
}

extern "C" void kernel_launch(void* const* d_in, const int* in_sizes, int n_in,
                              void* d_out, int out_size, void* d_ws, size_t ws_size,
                              hipStream_t stream)
{
  const float* x    = (const float*)d_in[0];
  const float* W_ih = (const float*)d_in[1];
  const float* W_hh = (const float*)d_in[2];
  const float* b_ih = (const float*)d_in[3];
  const float* b_hh = (const float*)d_in[4];
  const float* W_fc = (const float*)d_in[5];
  const float* b_fc = (const float*)d_in[6];
  float* out = (float*)d_out;

  // ws layout: h_pk 256KB | flags 8KB | h_lastT 128KB  (total 392KB)
  uint32_t* h_pk    = (uint32_t*)d_ws;
  int*      flags   = (int*)((char*)d_ws + (size_t)NGRP * 2 * BG * HDIM * 4);
  float*    h_lastT = (float*)((char*)d_ws + (size_t)NGRP * 2 * BG * HDIM * 4
                                           + (size_t)NGRP * WPG * 16 * 4);
  // flags poison (0xAAAAAAAA) is negative as int => polls (>= t, t>=1) can't
  // spuriously pass; monotonic step values make the protocol replay-safe.

  void* args[] = { (void*)&x, (void*)&W_ih, (void*)&W_hh, (void*)&b_ih, (void*)&b_hh,
                   (void*)&h_pk, (void*)&flags, (void*)&h_lastT };
  hipLaunchCooperativeKernel((const void*)lstm_persist, dim3(NWG), dim3(NTHR),
                             args, 0, stream);

  head_fc<<<dim3(1), dim3(640), 0, stream>>>(h_lastT, W_fc, b_fc, out);
}